// Round 12
// baseline (100.191 us; speedup 1.0000x reference)
//
#include <hip/hip_runtime.h>
#include <math.h>

#define T_SEQ 2048
#define HID   1024
#define NH    16
#define HD    64
#define NT    (T_SEQ / 64)

typedef __attribute__((ext_vector_type(8))) __bf16 bf16x8;
typedef __attribute__((ext_vector_type(4))) float  f32x4;
typedef __attribute__((ext_vector_type(8))) unsigned short u16x8;

#define GPTR(p) (const __attribute__((address_space(1))) void*)(p)
#define SPTR(p) (__attribute__((address_space(3))) void*)(p)

__device__ __forceinline__ unsigned short f2bf(float x) {
    unsigned u = __float_as_uint(x);
    u = (u + 0x7FFF + ((u >> 16) & 1)) >> 16;   // RNE
    return (unsigned short)u;
}
__device__ __forceinline__ float bf2f(unsigned short u) {
    return __uint_as_float((unsigned)u << 16);
}

// ---------------- prep1: f32->bf16 conversions (y<5) + fproj (y==5) ----------------
__global__ __launch_bounds__(256) void prep1(
    const float* __restrict__ hs,
    const float* __restrict__ Wq, const float* __restrict__ Wk,
    const float* __restrict__ Wv, const float* __restrict__ Wo,
    const float* __restrict__ Wf, const float* __restrict__ bfv,
    unsigned short* __restrict__ hsb, unsigned short* __restrict__ wqb,
    unsigned short* __restrict__ wkb, unsigned short* __restrict__ wvb,
    unsigned short* __restrict__ wob, float* __restrict__ f)
{
    const int y = blockIdx.y;
    if (y < 5) {
        const float* in; unsigned short* out; int n;
        switch (y) {
            case 0: in = hs; out = hsb; n = T_SEQ * HID; break;
            case 1: in = Wq; out = wqb; n = HID * HID;   break;
            case 2: in = Wk; out = wkb; n = HID * HID;   break;
            case 3: in = Wv; out = wvb; n = HID * HID;   break;
            default: in = Wo; out = wob; n = HID * 2 * HID; break;
        }
        const int stride = gridDim.x * blockDim.x;
        for (int i = blockIdx.x * blockDim.x + threadIdx.x; i < n / 4; i += stride) {
            float4 v = reinterpret_cast<const float4*>(in)[i];
            ushort4 r;
            r.x = f2bf(v.x); r.y = f2bf(v.y); r.z = f2bf(v.z); r.w = f2bf(v.w);
            reinterpret_cast<ushort4*>(out)[i] = r;
        }
    } else {
        const int t  = blockIdx.x;
        const int h  = threadIdx.x >> 4;
        const int sl = threadIdx.x & 15;
        const float4* hrow = reinterpret_cast<const float4*>(hs + (size_t)t * HID);
        const float4* wrow = reinterpret_cast<const float4*>(Wf + (size_t)h * HID);
        float s = 0.f;
        #pragma unroll
        for (int i = 0; i < 16; ++i) {
            float4 a = hrow[sl + i * 16];
            float4 b = wrow[sl + i * 16];
            s += a.x * b.x + a.y * b.y + a.z * b.z + a.w * b.w;
        }
        s += __shfl_xor(s, 1);
        s += __shfl_xor(s, 2);
        s += __shfl_xor(s, 4);
        s += __shfl_xor(s, 8);
        if (sl == 0) {
            float x = s + bfv[h];
            f[t * NH + h] = (x >= 0.f) ? -log1pf(expf(-x)) : (x - log1pf(expf(x)));
        }
    }
}

// -------- stage one operand tile (rows x BK cols bf16) into LDS (async) --------
template<int NCH, int ROWB>
__device__ __forceinline__ void stage_tile(const unsigned short* __restrict__ G, int K,
                                           int k0, unsigned short* lds, int tid, int w)
{
    #pragma unroll
    for (int j = 0; j < NCH; ++j) {
        const int idxb = j * 4096 + tid * 16;
        const int row  = idxb / ROWB;
        const int kbyt = idxb % ROWB;
        const int col  = (kbyt ^ ((row & 7) << 4)) >> 1;
        const int ldsh = (j * 4096 + w * 1024) >> 1;
        __builtin_amdgcn_global_load_lds(
            GPTR(G + (size_t)row * K + k0 + col), SPTR(lds + ldsh), 16, 0, 0);
    }
}

// ---------------- fused QKV GEMM: one block computes q,k,v for a 128xhead tile ----------------
// Shared A (hsb) staged once; 3 B operands; 48 MFMA per barrier pair.
// Outputs attention-native: qb [T][HID]*0.125, kb [NH][T][64], vt [NH][64][T].
__global__ __launch_bounds__(256) void gemm_qkv(
    const unsigned short* __restrict__ A,
    const unsigned short* __restrict__ Wq_, const unsigned short* __restrict__ Wk_,
    const unsigned short* __restrict__ Wv_,
    unsigned short* __restrict__ qb, unsigned short* __restrict__ kb,
    unsigned short* __restrict__ vt)
{
    constexpr int K = HID;
    __shared__ unsigned short Als[2][128 * 64];        // 32 KB
    __shared__ unsigned short Bls[3][2][64 * 64];      // 48 KB

    // XCD-aware bijective swizzle over 256 blocks (256 % 8 == 0)
    const int gx  = gridDim.x;
    const int nwg = gx * gridDim.y;
    const int lin = blockIdx.y * gx + blockIdx.x;
    const int cpx = nwg >> 3;
    const int sw  = (lin & 7) * cpx + (lin >> 3);
    const int bx  = sw % gx;      // head
    const int by  = sw / gx;      // T block

    const int tid = threadIdx.x;
    const int w   = tid >> 6;
    const int l   = tid & 63;
    const int bm  = by * 128;
    const int hh  = bx;
    const int wm  = (w >> 1) * 64;
    const int wn  = (w & 1) * 32;

    f32x4 acc[3][4][2];
    #pragma unroll
    for (int z = 0; z < 3; ++z)
        #pragma unroll
        for (int m = 0; m < 4; ++m)
            #pragma unroll
            for (int n = 0; n < 2; ++n) acc[z][m][n] = (f32x4){0.f, 0.f, 0.f, 0.f};

    const int frow = l & 15;
    const int kgrp = (l >> 4) * 16;
    const int swz  = (l & 7) << 4;

    const unsigned short* Ag  = A   + (size_t)bm * K;
    const unsigned short* Wgq = Wq_ + (size_t)hh * 64 * K;
    const unsigned short* Wgk = Wk_ + (size_t)hh * 64 * K;
    const unsigned short* Wgv = Wv_ + (size_t)hh * 64 * K;

    stage_tile<4, 128>(Ag,  K, 0, Als[0],    tid, w);
    stage_tile<2, 128>(Wgq, K, 0, Bls[0][0], tid, w);
    stage_tile<2, 128>(Wgk, K, 0, Bls[1][0], tid, w);
    stage_tile<2, 128>(Wgv, K, 0, Bls[2][0], tid, w);
    __syncthreads();

    int cur = 0;
    for (int it = 0; it < K / 64; ++it) {
        if (it + 1 < K / 64) {
            const int k1 = (it + 1) * 64;
            stage_tile<4, 128>(Ag,  K, k1, Als[cur ^ 1],    tid, w);
            stage_tile<2, 128>(Wgq, K, k1, Bls[0][cur ^ 1], tid, w);
            stage_tile<2, 128>(Wgk, K, k1, Bls[1][cur ^ 1], tid, w);
            stage_tile<2, 128>(Wgv, K, k1, Bls[2][cur ^ 1], tid, w);
        }
        #pragma unroll
        for (int ks = 0; ks < 2; ++ks) {
            bf16x8 af[4];
            #pragma unroll
            for (int m = 0; m < 4; ++m) {
                const int off = (wm + m * 16 + frow) * 128 + ((ks * 64 + kgrp) ^ swz);
                af[m] = *reinterpret_cast<const bf16x8*>((const char*)Als[cur] + off);
            }
            #pragma unroll
            for (int z = 0; z < 3; ++z) {
                bf16x8 bfr[2];
                #pragma unroll
                for (int n = 0; n < 2; ++n) {
                    const int off = (wn + n * 16 + frow) * 128 + ((ks * 64 + kgrp) ^ swz);
                    bfr[n] = *reinterpret_cast<const bf16x8*>((const char*)Bls[z][cur] + off);
                }
                #pragma unroll
                for (int m = 0; m < 4; ++m)
                    #pragma unroll
                    for (int n = 0; n < 2; ++n)
                        acc[z][m][n] = __builtin_amdgcn_mfma_f32_16x16x32_bf16(
                            af[m], bfr[n], acc[z][m][n], 0, 0, 0);
            }
        }
        __syncthreads();
        cur ^= 1;
    }

    const int r0 = (l >> 4) * 4;
    const int cc = l & 15;
    #pragma unroll
    for (int m = 0; m < 4; ++m) {
        const int t0 = bm + wm + m * 16 + r0;
        #pragma unroll
        for (int n = 0; n < 2; ++n) {
            const int d   = wn + n * 16 + cc;
            const int col = hh * 64 + d;
            #pragma unroll
            for (int r = 0; r < 4; ++r) {
                qb[(size_t)(t0 + r) * HID + col] = f2bf(acc[0][m][n][r] * 0.125f);
                kb[(size_t)hh * T_SEQ * HD + (size_t)(t0 + r) * HD + d] =
                    f2bf(acc[1][m][n][r]);
            }
            ushort4 pk;
            pk.x = f2bf(acc[2][m][n][0]); pk.y = f2bf(acc[2][m][n][1]);
            pk.z = f2bf(acc[2][m][n][2]); pk.w = f2bf(acc[2][m][n][3]);
            *reinterpret_cast<ushort4*>(
                vt + (size_t)hh * HD * T_SEQ + (size_t)d * T_SEQ + t0) = pk;
        }
    }
}

// ---------------- bf16 MFMA GEMM (out-projection), 2-phase dbuf, BK templated ----------------
template<int BM, int BN, int BK>
__global__ __launch_bounds__(256) void gemm_out(
    const unsigned short* __restrict__ A, const unsigned short* __restrict__ W,
    float* __restrict__ C, int M, int N, int K)
{
    constexpr int FM   = BM / 32;
    constexpr int FN   = BN / 32;
    constexpr int ROWB = BK * 2;
    constexpr int NCHA = BM * BK * 2 / 4096;
    constexpr int NCHB = BN * BK * 2 / 4096;
    constexpr int NKS  = BK / 32;

    __shared__ unsigned short Als[2][BM * BK];
    __shared__ unsigned short Bls[2][BN * BK];

    const int gx  = gridDim.x;
    const int nwg = gx * gridDim.y;
    const int lin = blockIdx.y * gx + blockIdx.x;
    const int cpx = nwg >> 3;
    const int sw  = (lin & 7) * cpx + (lin >> 3);
    const int bx  = sw % gx;
    const int by  = sw / gx;

    const int tid = threadIdx.x;
    const int w   = tid >> 6;
    const int l   = tid & 63;
    const int bm  = by * BM;
    const int bn  = bx * BN;
    const int wm  = (w >> 1) * (BM / 2);
    const int wn  = (w & 1) * (BN / 2);

    f32x4 acc[FM][FN];
    #pragma unroll
    for (int m = 0; m < FM; ++m)
        #pragma unroll
        for (int n = 0; n < FN; ++n) acc[m][n] = (f32x4){0.f, 0.f, 0.f, 0.f};

    const int frow = l & 15;
    const int kgrp = (l >> 4) * 16;
    const int swz  = (l & 7) << 4;

    const unsigned short* Ag = A + (size_t)bm * K;
    const unsigned short* Wg = W + (size_t)bn * K;

    const int NIT = K / BK;
    stage_tile<NCHA, ROWB>(Ag, K, 0, Als[0], tid, w);
    stage_tile<NCHB, ROWB>(Wg, K, 0, Bls[0], tid, w);
    __syncthreads();

    int cur = 0;
    for (int it = 0; it < NIT; ++it) {
        if (it + 1 < NIT) {
            stage_tile<NCHA, ROWB>(Ag, K, (it + 1) * BK, Als[cur ^ 1], tid, w);
            stage_tile<NCHB, ROWB>(Wg, K, (it + 1) * BK, Bls[cur ^ 1], tid, w);
        }
        const unsigned short* Ap = Als[cur];
        const unsigned short* Bp = Bls[cur];
        #pragma unroll
        for (int ks = 0; ks < NKS; ++ks) {
            bf16x8 af[FM], bfr[FN];
            #pragma unroll
            for (int m = 0; m < FM; ++m) {
                const int off = (wm + m * 16 + frow) * ROWB + ((ks * 64 + kgrp) ^ swz);
                af[m] = *reinterpret_cast<const bf16x8*>((const char*)Ap + off);
            }
            #pragma unroll
            for (int n = 0; n < FN; ++n) {
                const int off = (wn + n * 16 + frow) * ROWB + ((ks * 64 + kgrp) ^ swz);
                bfr[n] = *reinterpret_cast<const bf16x8*>((const char*)Bp + off);
            }
            #pragma unroll
            for (int m = 0; m < FM; ++m)
                #pragma unroll
                for (int n = 0; n < FN; ++n)
                    acc[m][n] = __builtin_amdgcn_mfma_f32_16x16x32_bf16(
                        af[m], bfr[n], acc[m][n], 0, 0, 0);
        }
        __syncthreads();
        cur ^= 1;
    }

    const int r0 = (l >> 4) * 4;
    const int cc = l & 15;
    #pragma unroll
    for (int m = 0; m < FM; ++m)
        #pragma unroll
        for (int n = 0; n < FN; ++n) {
            float* cp = C + (size_t)(bm + wm + m * 16 + r0) * N + bn + wn + n * 16 + cc;
            #pragma unroll
            for (int r = 0; r < 4; ++r) cp[(size_t)r * N] = acc[m][n][r];
        }
}

// ---------------- prep2: cumsum (blocks 0..31) + knorms (blocks 32..47) ----------------
__global__ __launch_bounds__(256) void prep2(const float* __restrict__ f,
                                             float* __restrict__ gcf,
                                             float* __restrict__ gcb,
                                             const unsigned short* __restrict__ kb,
                                             float* __restrict__ knmax)
{
    const int bid = blockIdx.x;
    if (bid < 32) {
        const int h   = bid >> 1;
        const int rev = bid & 1;
        float* out = rev ? gcb : gcf;
        const int wv   = threadIdx.x >> 6;
        const int lane = threadIdx.x & 63;
        __shared__ float wtot[4];
        float vals[8];
        float run = 0.f;
        #pragma unroll
        for (int c = 0; c < 8; ++c) {
            const int p = wv * 512 + c * 64 + lane;
            const int t = rev ? (T_SEQ - 1 - p) : p;
            float x = f[t * NH + h];
            #pragma unroll
            for (int off = 1; off < 64; off <<= 1) {
                float y = __shfl_up(x, off);
                if (lane >= off) x += y;
            }
            vals[c] = run + x;
            run += __shfl(x, 63);
        }
        if (lane == 0) wtot[wv] = run;
        __syncthreads();
        float prefix = 0.f;
        #pragma unroll
        for (int i = 0; i < 4; ++i) prefix += (i < wv) ? wtot[i] : 0.f;
        #pragma unroll
        for (int c = 0; c < 8; ++c) {
            const int p = wv * 512 + c * 64 + lane;
            const int t = rev ? (T_SEQ - 1 - p) : p;
            out[t * NH + h] = vals[c] + prefix;
        }
    } else {
        const int h    = bid - 32;
        const int tid  = threadIdx.x;
        const int wv   = tid >> 6;
        const int lane = tid & 63;
        __shared__ float wmax[4];
        float mx = 0.f;
        for (int t = tid; t < T_SEQ; t += 256) {
            const u16x8* kr = reinterpret_cast<const u16x8*>(
                kb + (size_t)h * T_SEQ * HD + (size_t)t * HD);
            float s = 0.f;
            #pragma unroll
            for (int i = 0; i < 8; ++i) {
                u16x8 v8 = kr[i];
                #pragma unroll
                for (int j = 0; j < 8; ++j) { float x = bf2f(v8[j]); s += x * x; }
            }
            mx = fmaxf(mx, s);
        }
        #pragma unroll
        for (int off = 32; off > 0; off >>= 1) mx = fmaxf(mx, __shfl_xor(mx, off));
        if (lane == 0) wmax[wv] = mx;
        __syncthreads();
        if (tid == 0) {
            float m = fmaxf(fmaxf(wmax[0], wmax[1]), fmaxf(wmax[2], wmax[3]));
            knmax[h] = sqrtf(m);
        }
    }
}

// ---------------- MFMA flash attention, bf16-native inputs (R8 staged form) ----------------
__global__ __launch_bounds__(256) void attn_flash(
    const unsigned short* __restrict__ qb, const unsigned short* __restrict__ kg,
    const unsigned short* __restrict__ vg,
    const float* __restrict__ gcf, const float* __restrict__ gcb,
    const float* __restrict__ knmax,
    unsigned short* __restrict__ ocat)
{
    const int dir = blockIdx.z;
    const float* gc = dir ? gcb : gcf;
    const int h   = blockIdx.y;
    const int qt  = blockIdx.x;
    const int q0  = qt * 64;
    const int tid = threadIdx.x;
    const int w   = tid >> 6;
    const int l   = tid & 63;
    const int lm  = l & 15;
    const int lg  = l >> 4;
    const int swz = (l & 7) << 4;

    __shared__ unsigned short Kls[64 * 64];
    __shared__ unsigned short Vls[64 * 64];
    __shared__ unsigned short Pls[64 * 64];
    __shared__ float gks[64];
    __shared__ float qbs[64];

    const size_t kgbase = (size_t)h * T_SEQ * HD;
    const size_t vgbase = (size_t)h * HD * T_SEQ;

    const int qrow_a = q0 + 16 * w + lm;
    bf16x8 aq[2];
    aq[0] = *reinterpret_cast<const bf16x8*>(qb + (size_t)qrow_a * HID + h * HD + lg * 8);
    aq[1] = *reinterpret_cast<const bf16x8*>(qb + (size_t)qrow_a * HID + h * HD + 32 + lg * 8);
    float qn2 = 0.f;
    #pragma unroll
    for (int ks = 0; ks < 2; ++ks) {
        u16x8 uv = *reinterpret_cast<const u16x8*>(&aq[ks]);
        #pragma unroll
        for (int j = 0; j < 8; ++j) { float x = bf2f(uv[j]); qn2 += x * x; }
    }
    qn2 += __shfl_xor(qn2, 16);
    qn2 += __shfl_xor(qn2, 32);
    if (lg == 0) qbs[16 * w + lm] = sqrtf(qn2) * knmax[h];

    float gq_r[4];
    #pragma unroll
    for (int reg = 0; reg < 4; ++reg)
        gq_r[reg] = gc[(q0 + 16 * w + lg * 4 + reg) * NH + h];

    float mrun[4], lrun[4];
    #pragma unroll
    for (int reg = 0; reg < 4; ++reg) { mrun[reg] = -1e30f; lrun[reg] = 0.f; }
    f32x4 acc[4];
    #pragma unroll
    for (int db = 0; db < 4; ++db) acc[db] = (f32x4){0.f, 0.f, 0.f, 0.f};

    const int stp = dir ? 1 : -1;
    for (int kt = qt; kt >= 0 && kt < NT; kt += stp) {
        const int k0 = kt * 64;

        #pragma unroll
        for (int j = 0; j < 2; ++j) {
            const int idxb = j * 4096 + tid * 16;
            const int row  = idxb >> 7;
            const int kbyt = idxb & 127;
            const int scol = (kbyt ^ ((row & 7) << 4)) >> 1;
            const int ldsh = (j * 4096 + w * 1024) >> 1;
            __builtin_amdgcn_global_load_lds(
                GPTR(kg + kgbase + (size_t)(k0 + row) * HD + scol),
                SPTR(Kls + ldsh), 16, 0, 0);
            __builtin_amdgcn_global_load_lds(
                GPTR(vg + vgbase + (size_t)row * T_SEQ + k0 + scol),
                SPTR(Vls + ldsh), 16, 0, 0);
        }
        if (w == 0)
            __builtin_amdgcn_global_load_lds(
                GPTR(gc + (size_t)(k0 + l) * NH + h), SPTR(gks), 4, 0, 0);
        __syncthreads();

        f32x4 s[4];
        #pragma unroll
        for (int cb = 0; cb < 4; ++cb) {
            bf16x8 b0 = *reinterpret_cast<const bf16x8*>(
                (char*)Kls + (cb * 16 + lm) * 128 + ((lg * 16) ^ swz));
            bf16x8 b1 = *reinterpret_cast<const bf16x8*>(
                (char*)Kls + (cb * 16 + lm) * 128 + ((64 + lg * 16) ^ swz));
            f32x4 z = (f32x4){0.f, 0.f, 0.f, 0.f};
            z = __builtin_amdgcn_mfma_f32_16x16x32_bf16(aq[0], b0, z, 0, 0, 0);
            s[cb] = __builtin_amdgcn_mfma_f32_16x16x32_bf16(aq[1], b1, z, 0, 0, 0);
        }

        float gk_c[4];
        #pragma unroll
        for (int cb = 0; cb < 4; ++cb) gk_c[cb] = gks[cb * 16 + lm];
        float sv[4][4];
        const bool diag = (kt == qt);
        #pragma unroll
        for (int cb = 0; cb < 4; ++cb)
            #pragma unroll
            for (int reg = 0; reg < 4; ++reg) {
                float x = s[cb][reg] + gq_r[reg] - gk_c[cb];
                if (diag) {
                    const int c_loc = cb * 16 + lm;
                    const int r_loc = 16 * w + lg * 4 + reg;
                    const bool valid = dir ? (c_loc >= r_loc) : (c_loc <= r_loc);
                    x = valid ? x : -1e30f;
                }
                sv[cb][reg] = x;
            }

        float corr[4], mnew[4];
        #pragma unroll
        for (int reg = 0; reg < 4; ++reg) {
            float rm = fmaxf(fmaxf(sv[0][reg], sv[1][reg]), fmaxf(sv[2][reg], sv[3][reg]));
            rm = fmaxf(rm, __shfl_xor(rm, 1));
            rm = fmaxf(rm, __shfl_xor(rm, 2));
            rm = fmaxf(rm, __shfl_xor(rm, 4));
            rm = fmaxf(rm, __shfl_xor(rm, 8));
            mnew[reg] = fmaxf(mrun[reg], rm);
            corr[reg] = __expf(mrun[reg] - mnew[reg]);
            mrun[reg] = mnew[reg];
        }
        float psum[4] = {0.f, 0.f, 0.f, 0.f};
        #pragma unroll
        for (int cb = 0; cb < 4; ++cb)
            #pragma unroll
            for (int reg = 0; reg < 4; ++reg) {
                const float p = __expf(sv[cb][reg] - mnew[reg]);
                psum[reg] += p;
                const int r_loc = 16 * w + lg * 4 + reg;
                *reinterpret_cast<unsigned short*>(
                    (char*)Pls + r_loc * 128 + ((cb * 32 + lm * 2) ^ ((r_loc & 7) << 4))) = f2bf(p);
            }
        #pragma unroll
        for (int reg = 0; reg < 4; ++reg) {
            float ps = psum[reg];
            ps += __shfl_xor(ps, 1);
            ps += __shfl_xor(ps, 2);
            ps += __shfl_xor(ps, 4);
            ps += __shfl_xor(ps, 8);
            lrun[reg] = lrun[reg] * corr[reg] + ps;
        }
        #pragma unroll
        for (int db = 0; db < 4; ++db)
            #pragma unroll
            for (int reg = 0; reg < 4; ++reg) acc[db][reg] *= corr[reg];

        bf16x8 ap[2];
        #pragma unroll
        for (int ks = 0; ks < 2; ++ks)
            ap[ks] = *reinterpret_cast<const bf16x8*>(
                (char*)Pls + (16 * w + lm) * 128 + ((ks * 64 + lg * 16) ^ swz));
        #pragma unroll
        for (int db = 0; db < 4; ++db) {
            bf16x8 bv0 = *reinterpret_cast<const bf16x8*>(
                (char*)Vls + (db * 16 + lm) * 128 + ((lg * 16) ^ swz));
            bf16x8 bv1 = *reinterpret_cast<const bf16x8*>(
                (char*)Vls + (db * 16 + lm) * 128 + ((64 + lg * 16) ^ swz));
            acc[db] = __builtin_amdgcn_mfma_f32_16x16x32_bf16(ap[0], bv0, acc[db], 0, 0, 0);
            acc[db] = __builtin_amdgcn_mfma_f32_16x16x32_bf16(ap[1], bv1, acc[db], 0, 0, 0);
        }

        const int nkt = kt + stp;
        if (nkt >= 0 && nkt < NT) {
            const float gkedge = dir ? gc[(nkt * 64) * NH + h]
                                     : gc[(nkt * 64 + 63) * NH + h];
            int pred = 0;
            #pragma unroll
            for (int reg = 0; reg < 4; ++reg) {
                const float qbv = qbs[16 * w + lg * 4 + reg];
                pred |= (qbv + gq_r[reg] - gkedge) >= (mrun[reg] - 15.f);
            }
            if (!__syncthreads_or(pred)) break;
        }
    }

    float inv[4];
    #pragma unroll
    for (int reg = 0; reg < 4; ++reg) inv[reg] = 1.f / lrun[reg];
    #pragma unroll
    for (int db = 0; db < 4; ++db)
        #pragma unroll
        for (int reg = 0; reg < 4; ++reg) {
            const int row = q0 + 16 * w + lg * 4 + reg;
            const int col = db * 16 + lm;
            ocat[(size_t)row * (2 * HID) + dir * HID + h * HD + col] =
                f2bf(acc[db][reg] * inv[reg]);
        }
}

// ---------------- launch ----------------
extern "C" void kernel_launch(void* const* d_in, const int* in_sizes, int n_in,
                              void* d_out, int out_size, void* d_ws, size_t ws_size,
                              hipStream_t stream)
{
    (void)in_sizes; (void)n_in; (void)out_size; (void)ws_size;
    const float* hs = (const float*)d_in[0];
    const float* Wq = (const float*)d_in[1];
    const float* Wk = (const float*)d_in[2];
    const float* Wv = (const float*)d_in[3];
    const float* Wf = (const float*)d_in[4];
    const float* bf = (const float*)d_in[5];
    const float* Wo = (const float*)d_in[6];
    float* out = (float*)d_out;

    float* ws    = (float*)d_ws;
    float* f     = ws;
    float* gcf   = f   + (size_t)T_SEQ * NH;
    float* gcb   = gcf + (size_t)T_SEQ * NH;
    float* knmax = gcb + (size_t)T_SEQ * NH;
    unsigned short* hsb  = (unsigned short*)(knmax + 64);
    unsigned short* wqb  = hsb + (size_t)T_SEQ * HID;
    unsigned short* wkb  = wqb + (size_t)HID * HID;
    unsigned short* wvb  = wkb + (size_t)HID * HID;
    unsigned short* wob  = wvb + (size_t)HID * HID;
    unsigned short* qb   = wob + (size_t)HID * 2 * HID;
    unsigned short* kb   = qb  + (size_t)T_SEQ * HID;
    unsigned short* vt   = kb  + (size_t)T_SEQ * HID;
    unsigned short* ocat = vt  + (size_t)T_SEQ * HID;

    // L1: conversions + fproj fused
    prep1<<<dim3(2048, 6), 256, 0, stream>>>(
        hs, Wq, Wk, Wv, Wo, Wf, bf, hsb, wqb, wkb, wvb, wob, f);

    // L2: fused QKV (shared-A, 3 outputs) -> attention-native layouts
    gemm_qkv<<<dim3(NH, T_SEQ / 128), 256, 0, stream>>>(
        hsb, wqb, wkb, wvb, qb, kb, vt);

    // L3: cumsum + knorms fused
    prep2<<<48, 256, 0, stream>>>(f, gcf, gcb, kb, knmax);

    // L4: attention, both dirs (staged, R8 form)
    attn_flash<<<dim3(NT, NH, 2), 256, 0, stream>>>(qb, kb, vt, gcf, gcb, knmax, ocat);

    // L5: out = ocat @ Wo^T (64x64 tile, BK=128, dbuf)
    gemm_out<64, 64, 128><<<dim3(HID / 64, T_SEQ / 64), 256, 0, stream>>>(
        ocat, wob, out, T_SEQ, HID, 2 * HID);
}

// Round 13
// 99.630 us; speedup vs baseline: 1.0056x; 1.0056x over previous
//
#include <hip/hip_runtime.h>
#include <math.h>

#define T_SEQ 2048
#define HID   1024
#define NH    16
#define HD    64
#define NT    (T_SEQ / 64)

typedef __attribute__((ext_vector_type(8))) __bf16 bf16x8;
typedef __attribute__((ext_vector_type(4))) float  f32x4;
typedef __attribute__((ext_vector_type(8))) unsigned short u16x8;

#define GPTR(p) (const __attribute__((address_space(1))) void*)(p)
#define SPTR(p) (__attribute__((address_space(3))) void*)(p)

__device__ __forceinline__ unsigned short f2bf(float x) {
    unsigned u = __float_as_uint(x);
    u = (u + 0x7FFF + ((u >> 16) & 1)) >> 16;   // RNE
    return (unsigned short)u;
}
__device__ __forceinline__ float bf2f(unsigned short u) {
    return __uint_as_float((unsigned)u << 16);
}

// ---------------- prep1: f32->bf16 conversions (y<5) + fproj (y==5) ----------------
// 512-wide grid, grid-stride; fproj handles 4 t-values per block.
__global__ __launch_bounds__(256) void prep1(
    const float* __restrict__ hs,
    const float* __restrict__ Wq, const float* __restrict__ Wk,
    const float* __restrict__ Wv, const float* __restrict__ Wo,
    const float* __restrict__ Wf, const float* __restrict__ bfv,
    unsigned short* __restrict__ hsb, unsigned short* __restrict__ wqb,
    unsigned short* __restrict__ wkb, unsigned short* __restrict__ wvb,
    unsigned short* __restrict__ wob, float* __restrict__ f)
{
    const int y = blockIdx.y;
    if (y < 5) {
        const float* in; unsigned short* out; int n;
        switch (y) {
            case 0: in = hs; out = hsb; n = T_SEQ * HID; break;
            case 1: in = Wq; out = wqb; n = HID * HID;   break;
            case 2: in = Wk; out = wkb; n = HID * HID;   break;
            case 3: in = Wv; out = wvb; n = HID * HID;   break;
            default: in = Wo; out = wob; n = HID * 2 * HID; break;
        }
        const int stride = gridDim.x * blockDim.x;
        for (int i = blockIdx.x * blockDim.x + threadIdx.x; i < n / 4; i += stride) {
            float4 v = reinterpret_cast<const float4*>(in)[i];
            ushort4 r;
            r.x = f2bf(v.x); r.y = f2bf(v.y); r.z = f2bf(v.z); r.w = f2bf(v.w);
            reinterpret_cast<ushort4*>(out)[i] = r;
        }
    } else {
        const int h  = threadIdx.x >> 4;
        const int sl = threadIdx.x & 15;
        const float4* wrow = reinterpret_cast<const float4*>(Wf + (size_t)h * HID);
        #pragma unroll
        for (int ti = 0; ti < 4; ++ti) {
            const int t = blockIdx.x + ti * 512;
            const float4* hrow = reinterpret_cast<const float4*>(hs + (size_t)t * HID);
            float s = 0.f;
            #pragma unroll
            for (int i = 0; i < 16; ++i) {
                float4 a = hrow[sl + i * 16];
                float4 b = wrow[sl + i * 16];
                s += a.x * b.x + a.y * b.y + a.z * b.z + a.w * b.w;
            }
            s += __shfl_xor(s, 1);
            s += __shfl_xor(s, 2);
            s += __shfl_xor(s, 4);
            s += __shfl_xor(s, 8);
            if (sl == 0) {
                float x = s + bfv[h];
                f[t * NH + h] = (x >= 0.f) ? -log1pf(expf(-x)) : (x - log1pf(expf(x)));
            }
        }
    }
}

// -------- stage one operand tile (rows x BK cols bf16) into LDS (async) --------
template<int NCH, int ROWB>
__device__ __forceinline__ void stage_tile(const unsigned short* __restrict__ G, int K,
                                           int k0, unsigned short* lds, int tid, int w)
{
    #pragma unroll
    for (int j = 0; j < NCH; ++j) {
        const int idxb = j * 4096 + tid * 16;
        const int row  = idxb / ROWB;
        const int kbyt = idxb % ROWB;
        const int col  = (kbyt ^ ((row & 7) << 4)) >> 1;
        const int ldsh = (j * 4096 + w * 1024) >> 1;
        __builtin_amdgcn_global_load_lds(
            GPTR(G + (size_t)row * K + k0 + col), SPTR(lds + ldsh), 16, 0, 0);
    }
}

// ---------------- bf16 MFMA GEMM, 2-phase double-buffered, templated BK ----------------
// EMODE 0 (qkv): z=0 -> qb [T][HID]*0.125; z=1 -> kb [NH][T][64]; z=2 -> vt [NH][64][T].
// EMODE 1: f32 C store. Grid pre-swizzled for XCD locality (nwg%8==0 required).
template<int BM, int BN, int BK, int EMODE>
__global__ __launch_bounds__(256) void gemm_mfma_bt(
    const unsigned short* __restrict__ A,
    const unsigned short* __restrict__ W0, const unsigned short* __restrict__ W1,
    const unsigned short* __restrict__ W2,
    float* __restrict__ C,
    unsigned short* __restrict__ qb, unsigned short* __restrict__ kb,
    unsigned short* __restrict__ vt,
    int M, int N, int K)
{
    const unsigned short* W = blockIdx.z == 0 ? W0 : (blockIdx.z == 1 ? W1 : W2);

    constexpr int FM   = BM / 32;
    constexpr int FN   = BN / 32;
    constexpr int ROWB = BK * 2;
    constexpr int NCHA = BM * BK * 2 / 4096;
    constexpr int NCHB = BN * BK * 2 / 4096;
    constexpr int NKS  = BK / 32;

    __shared__ unsigned short Als[2][BM * BK];
    __shared__ unsigned short Bls[2][BN * BK];

    // XCD-aware bijective swizzle (nwg % 8 == 0)
    const int gx  = gridDim.x;
    const int nwg = gx * gridDim.y;
    const int lin = blockIdx.y * gx + blockIdx.x;
    const int cpx = nwg >> 3;
    const int sw  = (lin & 7) * cpx + (lin >> 3);
    const int bx  = sw % gx;
    const int by  = sw / gx;

    const int tid = threadIdx.x;
    const int w   = tid >> 6;
    const int l   = tid & 63;
    const int bm  = by * BM;
    const int bn  = bx * BN;
    const int wm  = (w >> 1) * (BM / 2);
    const int wn  = (w & 1) * (BN / 2);

    f32x4 acc[FM][FN];
    #pragma unroll
    for (int m = 0; m < FM; ++m)
        #pragma unroll
        for (int n = 0; n < FN; ++n) acc[m][n] = (f32x4){0.f, 0.f, 0.f, 0.f};

    const int frow = l & 15;
    const int kgrp = (l >> 4) * 16;
    const int swz  = (l & 7) << 4;

    const unsigned short* Ag = A + (size_t)bm * K;
    const unsigned short* Wg = W + (size_t)bn * K;

    const int NIT = K / BK;
    stage_tile<NCHA, ROWB>(Ag, K, 0, Als[0], tid, w);
    stage_tile<NCHB, ROWB>(Wg, K, 0, Bls[0], tid, w);
    __syncthreads();           // vmcnt drained -> buf0 ready

    int cur = 0;
    for (int it = 0; it < NIT; ++it) {
        if (it + 1 < NIT) {    // issue next-tile loads before compute (overlap)
            stage_tile<NCHA, ROWB>(Ag, K, (it + 1) * BK, Als[cur ^ 1], tid, w);
            stage_tile<NCHB, ROWB>(Wg, K, (it + 1) * BK, Bls[cur ^ 1], tid, w);
        }
        const unsigned short* Ap = Als[cur];
        const unsigned short* Bp = Bls[cur];
        #pragma unroll
        for (int ks = 0; ks < NKS; ++ks) {
            bf16x8 af[FM], bfr[FN];
            #pragma unroll
            for (int m = 0; m < FM; ++m) {
                const int off = (wm + m * 16 + frow) * ROWB + ((ks * 64 + kgrp) ^ swz);
                af[m] = *reinterpret_cast<const bf16x8*>((const char*)Ap + off);
            }
            #pragma unroll
            for (int n = 0; n < FN; ++n) {
                const int off = (wn + n * 16 + frow) * ROWB + ((ks * 64 + kgrp) ^ swz);
                bfr[n] = *reinterpret_cast<const bf16x8*>((const char*)Bp + off);
            }
            #pragma unroll
            for (int m = 0; m < FM; ++m)
                #pragma unroll
                for (int n = 0; n < FN; ++n)
                    acc[m][n] = __builtin_amdgcn_mfma_f32_16x16x32_bf16(
                        af[m], bfr[n], acc[m][n], 0, 0, 0);
        }
        __syncthreads();       // drains vmcnt: next buffer ready; cur reads done
        cur ^= 1;
    }

    const int r0 = (l >> 4) * 4;
    const int cc = l & 15;
    if (EMODE == 1) {
        #pragma unroll
        for (int m = 0; m < FM; ++m)
            #pragma unroll
            for (int n = 0; n < FN; ++n) {
                float* cp = C + (size_t)(bm + wm + m * 16 + r0) * N + bn + wn + n * 16 + cc;
                #pragma unroll
                for (int r = 0; r < 4; ++r) cp[(size_t)r * N] = acc[m][n][r];
            }
    } else {
        const int z = blockIdx.z;
        if (z == 0) {
            #pragma unroll
            for (int m = 0; m < FM; ++m) {
                const int t0 = bm + wm + m * 16 + r0;
                #pragma unroll
                for (int n = 0; n < FN; ++n) {
                    const int col = bn + wn + n * 16 + cc;
                    #pragma unroll
                    for (int r = 0; r < 4; ++r)
                        qb[(size_t)(t0 + r) * HID + col] = f2bf(acc[m][n][r] * 0.125f);
                }
            }
        } else if (z == 1) {
            #pragma unroll
            for (int m = 0; m < FM; ++m) {
                const int t0 = bm + wm + m * 16 + r0;
                #pragma unroll
                for (int n = 0; n < FN; ++n) {
                    const int col = bn + wn + n * 16 + cc;
                    const int hh  = col >> 6;
                    const int d   = col & 63;
                    #pragma unroll
                    for (int r = 0; r < 4; ++r)
                        kb[(size_t)hh * T_SEQ * HD + (size_t)(t0 + r) * HD + d] =
                            f2bf(acc[m][n][r]);
                }
            }
        } else {
            #pragma unroll
            for (int m = 0; m < FM; ++m) {
                const int t0 = bm + wm + m * 16 + r0;
                #pragma unroll
                for (int n = 0; n < FN; ++n) {
                    const int col = bn + wn + n * 16 + cc;
                    const int hh  = col >> 6;
                    const int d   = col & 63;
                    ushort4 pk;
                    pk.x = f2bf(acc[m][n][0]); pk.y = f2bf(acc[m][n][1]);
                    pk.z = f2bf(acc[m][n][2]); pk.w = f2bf(acc[m][n][3]);
                    *reinterpret_cast<ushort4*>(
                        vt + (size_t)hh * HD * T_SEQ + (size_t)d * T_SEQ + t0) = pk;
                }
            }
        }
    }
}

// ---------------- prep2: cumsum (blocks 0..31) + knorms (blocks 32..47) ----------------
__global__ __launch_bounds__(256) void prep2(const float* __restrict__ f,
                                             float* __restrict__ gcf,
                                             float* __restrict__ gcb,
                                             const unsigned short* __restrict__ kb,
                                             float* __restrict__ knmax)
{
    const int bid = blockIdx.x;
    if (bid < 32) {
        const int h   = bid >> 1;
        const int rev = bid & 1;
        float* out = rev ? gcb : gcf;
        const int wv   = threadIdx.x >> 6;
        const int lane = threadIdx.x & 63;
        __shared__ float wtot[4];
        float vals[8];
        float run = 0.f;
        #pragma unroll
        for (int c = 0; c < 8; ++c) {
            const int p = wv * 512 + c * 64 + lane;
            const int t = rev ? (T_SEQ - 1 - p) : p;
            float x = f[t * NH + h];
            #pragma unroll
            for (int off = 1; off < 64; off <<= 1) {
                float y = __shfl_up(x, off);
                if (lane >= off) x += y;
            }
            vals[c] = run + x;
            run += __shfl(x, 63);
        }
        if (lane == 0) wtot[wv] = run;
        __syncthreads();
        float prefix = 0.f;
        #pragma unroll
        for (int i = 0; i < 4; ++i) prefix += (i < wv) ? wtot[i] : 0.f;
        #pragma unroll
        for (int c = 0; c < 8; ++c) {
            const int p = wv * 512 + c * 64 + lane;
            const int t = rev ? (T_SEQ - 1 - p) : p;
            out[t * NH + h] = vals[c] + prefix;
        }
    } else {
        const int h    = bid - 32;
        const int tid  = threadIdx.x;
        const int wv   = tid >> 6;
        const int lane = tid & 63;
        __shared__ float wmax[4];
        float mx = 0.f;
        for (int t = tid; t < T_SEQ; t += 256) {
            const u16x8* kr = reinterpret_cast<const u16x8*>(
                kb + (size_t)h * T_SEQ * HD + (size_t)t * HD);
            float s = 0.f;
            #pragma unroll
            for (int i = 0; i < 8; ++i) {
                u16x8 v8 = kr[i];
                #pragma unroll
                for (int j = 0; j < 8; ++j) { float x = bf2f(v8[j]); s += x * x; }
            }
            mx = fmaxf(mx, s);
        }
        #pragma unroll
        for (int off = 32; off > 0; off >>= 1) mx = fmaxf(mx, __shfl_xor(mx, off));
        if (lane == 0) wmax[wv] = mx;
        __syncthreads();
        if (tid == 0) {
            float m = fmaxf(fmaxf(wmax[0], wmax[1]), fmaxf(wmax[2], wmax[3]));
            knmax[h] = sqrtf(m);
        }
    }
}

// ---------------- MFMA flash attention, bf16-native inputs (R8 staged form) ----------------
__global__ __launch_bounds__(256) void attn_flash(
    const unsigned short* __restrict__ qb, const unsigned short* __restrict__ kg,
    const unsigned short* __restrict__ vg,
    const float* __restrict__ gcf, const float* __restrict__ gcb,
    const float* __restrict__ knmax,
    unsigned short* __restrict__ ocat)
{
    const int dir = blockIdx.z;
    const float* gc = dir ? gcb : gcf;
    const int h   = blockIdx.y;
    const int qt  = blockIdx.x;
    const int q0  = qt * 64;
    const int tid = threadIdx.x;
    const int w   = tid >> 6;
    const int l   = tid & 63;
    const int lm  = l & 15;
    const int lg  = l >> 4;
    const int swz = (l & 7) << 4;

    __shared__ unsigned short Kls[64 * 64];
    __shared__ unsigned short Vls[64 * 64];
    __shared__ unsigned short Pls[64 * 64];
    __shared__ float gks[64];
    __shared__ float qbs[64];

    const size_t kgbase = (size_t)h * T_SEQ * HD;
    const size_t vgbase = (size_t)h * HD * T_SEQ;

    const int qrow_a = q0 + 16 * w + lm;
    bf16x8 aq[2];
    aq[0] = *reinterpret_cast<const bf16x8*>(qb + (size_t)qrow_a * HID + h * HD + lg * 8);
    aq[1] = *reinterpret_cast<const bf16x8*>(qb + (size_t)qrow_a * HID + h * HD + 32 + lg * 8);
    float qn2 = 0.f;
    #pragma unroll
    for (int ks = 0; ks < 2; ++ks) {
        u16x8 uv = *reinterpret_cast<const u16x8*>(&aq[ks]);
        #pragma unroll
        for (int j = 0; j < 8; ++j) { float x = bf2f(uv[j]); qn2 += x * x; }
    }
    qn2 += __shfl_xor(qn2, 16);
    qn2 += __shfl_xor(qn2, 32);
    if (lg == 0) qbs[16 * w + lm] = sqrtf(qn2) * knmax[h];

    float gq_r[4];
    #pragma unroll
    for (int reg = 0; reg < 4; ++reg)
        gq_r[reg] = gc[(q0 + 16 * w + lg * 4 + reg) * NH + h];

    float mrun[4], lrun[4];
    #pragma unroll
    for (int reg = 0; reg < 4; ++reg) { mrun[reg] = -1e30f; lrun[reg] = 0.f; }
    f32x4 acc[4];
    #pragma unroll
    for (int db = 0; db < 4; ++db) acc[db] = (f32x4){0.f, 0.f, 0.f, 0.f};

    const int stp = dir ? 1 : -1;
    for (int kt = qt; kt >= 0 && kt < NT; kt += stp) {
        const int k0 = kt * 64;

        #pragma unroll
        for (int j = 0; j < 2; ++j) {
            const int idxb = j * 4096 + tid * 16;
            const int row  = idxb >> 7;
            const int kbyt = idxb & 127;
            const int scol = (kbyt ^ ((row & 7) << 4)) >> 1;
            const int ldsh = (j * 4096 + w * 1024) >> 1;
            __builtin_amdgcn_global_load_lds(
                GPTR(kg + kgbase + (size_t)(k0 + row) * HD + scol),
                SPTR(Kls + ldsh), 16, 0, 0);
            __builtin_amdgcn_global_load_lds(
                GPTR(vg + vgbase + (size_t)row * T_SEQ + k0 + scol),
                SPTR(Vls + ldsh), 16, 0, 0);
        }
        if (w == 0)
            __builtin_amdgcn_global_load_lds(
                GPTR(gc + (size_t)(k0 + l) * NH + h), SPTR(gks), 4, 0, 0);
        __syncthreads();

        f32x4 s[4];
        #pragma unroll
        for (int cb = 0; cb < 4; ++cb) {
            bf16x8 b0 = *reinterpret_cast<const bf16x8*>(
                (char*)Kls + (cb * 16 + lm) * 128 + ((lg * 16) ^ swz));
            bf16x8 b1 = *reinterpret_cast<const bf16x8*>(
                (char*)Kls + (cb * 16 + lm) * 128 + ((64 + lg * 16) ^ swz));
            f32x4 z = (f32x4){0.f, 0.f, 0.f, 0.f};
            z = __builtin_amdgcn_mfma_f32_16x16x32_bf16(aq[0], b0, z, 0, 0, 0);
            s[cb] = __builtin_amdgcn_mfma_f32_16x16x32_bf16(aq[1], b1, z, 0, 0, 0);
        }

        float gk_c[4];
        #pragma unroll
        for (int cb = 0; cb < 4; ++cb) gk_c[cb] = gks[cb * 16 + lm];
        float sv[4][4];
        const bool diag = (kt == qt);
        #pragma unroll
        for (int cb = 0; cb < 4; ++cb)
            #pragma unroll
            for (int reg = 0; reg < 4; ++reg) {
                float x = s[cb][reg] + gq_r[reg] - gk_c[cb];
                if (diag) {
                    const int c_loc = cb * 16 + lm;
                    const int r_loc = 16 * w + lg * 4 + reg;
                    const bool valid = dir ? (c_loc >= r_loc) : (c_loc <= r_loc);
                    x = valid ? x : -1e30f;
                }
                sv[cb][reg] = x;
            }

        float corr[4], mnew[4];
        #pragma unroll
        for (int reg = 0; reg < 4; ++reg) {
            float rm = fmaxf(fmaxf(sv[0][reg], sv[1][reg]), fmaxf(sv[2][reg], sv[3][reg]));
            rm = fmaxf(rm, __shfl_xor(rm, 1));
            rm = fmaxf(rm, __shfl_xor(rm, 2));
            rm = fmaxf(rm, __shfl_xor(rm, 4));
            rm = fmaxf(rm, __shfl_xor(rm, 8));
            mnew[reg] = fmaxf(mrun[reg], rm);
            corr[reg] = __expf(mrun[reg] - mnew[reg]);
            mrun[reg] = mnew[reg];
        }
        float psum[4] = {0.f, 0.f, 0.f, 0.f};
        #pragma unroll
        for (int cb = 0; cb < 4; ++cb)
            #pragma unroll
            for (int reg = 0; reg < 4; ++reg) {
                const float p = __expf(sv[cb][reg] - mnew[reg]);
                psum[reg] += p;
                const int r_loc = 16 * w + lg * 4 + reg;
                *reinterpret_cast<unsigned short*>(
                    (char*)Pls + r_loc * 128 + ((cb * 32 + lm * 2) ^ ((r_loc & 7) << 4))) = f2bf(p);
            }
        #pragma unroll
        for (int reg = 0; reg < 4; ++reg) {
            float ps = psum[reg];
            ps += __shfl_xor(ps, 1);
            ps += __shfl_xor(ps, 2);
            ps += __shfl_xor(ps, 4);
            ps += __shfl_xor(ps, 8);
            lrun[reg] = lrun[reg] * corr[reg] + ps;
        }
        #pragma unroll
        for (int db = 0; db < 4; ++db)
            #pragma unroll
            for (int reg = 0; reg < 4; ++reg) acc[db][reg] *= corr[reg];

        bf16x8 ap[2];
        #pragma unroll
        for (int ks = 0; ks < 2; ++ks)
            ap[ks] = *reinterpret_cast<const bf16x8*>(
                (char*)Pls + (16 * w + lm) * 128 + ((ks * 64 + lg * 16) ^ swz));
        #pragma unroll
        for (int db = 0; db < 4; ++db) {
            bf16x8 bv0 = *reinterpret_cast<const bf16x8*>(
                (char*)Vls + (db * 16 + lm) * 128 + ((lg * 16) ^ swz));
            bf16x8 bv1 = *reinterpret_cast<const bf16x8*>(
                (char*)Vls + (db * 16 + lm) * 128 + ((64 + lg * 16) ^ swz));
            acc[db] = __builtin_amdgcn_mfma_f32_16x16x32_bf16(ap[0], bv0, acc[db], 0, 0, 0);
            acc[db] = __builtin_amdgcn_mfma_f32_16x16x32_bf16(ap[1], bv1, acc[db], 0, 0, 0);
        }

        const int nkt = kt + stp;
        if (nkt >= 0 && nkt < NT) {
            const float gkedge = dir ? gc[(nkt * 64) * NH + h]
                                     : gc[(nkt * 64 + 63) * NH + h];
            int pred = 0;
            #pragma unroll
            for (int reg = 0; reg < 4; ++reg) {
                const float qbv = qbs[16 * w + lg * 4 + reg];
                pred |= (qbv + gq_r[reg] - gkedge) >= (mrun[reg] - 15.f);
            }
            if (!__syncthreads_or(pred)) break;
        }
    }

    float inv[4];
    #pragma unroll
    for (int reg = 0; reg < 4; ++reg) inv[reg] = 1.f / lrun[reg];
    #pragma unroll
    for (int db = 0; db < 4; ++db)
        #pragma unroll
        for (int reg = 0; reg < 4; ++reg) {
            const int row = q0 + 16 * w + lg * 4 + reg;
            const int col = db * 16 + lm;
            ocat[(size_t)row * (2 * HID) + dir * HID + h * HD + col] =
                f2bf(acc[db][reg] * inv[reg]);
        }
}

// ---------------- launch ----------------
extern "C" void kernel_launch(void* const* d_in, const int* in_sizes, int n_in,
                              void* d_out, int out_size, void* d_ws, size_t ws_size,
                              hipStream_t stream)
{
    (void)in_sizes; (void)n_in; (void)out_size; (void)ws_size;
    const float* hs = (const float*)d_in[0];
    const float* Wq = (const float*)d_in[1];
    const float* Wk = (const float*)d_in[2];
    const float* Wv = (const float*)d_in[3];
    const float* Wf = (const float*)d_in[4];
    const float* bf = (const float*)d_in[5];
    const float* Wo = (const float*)d_in[6];
    float* out = (float*)d_out;

    float* ws    = (float*)d_ws;
    float* f     = ws;
    float* gcf   = f   + (size_t)T_SEQ * NH;
    float* gcb   = gcf + (size_t)T_SEQ * NH;
    float* knmax = gcb + (size_t)T_SEQ * NH;
    unsigned short* hsb  = (unsigned short*)(knmax + 64);
    unsigned short* wqb  = hsb + (size_t)T_SEQ * HID;
    unsigned short* wkb  = wqb + (size_t)HID * HID;
    unsigned short* wvb  = wkb + (size_t)HID * HID;
    unsigned short* wob  = wvb + (size_t)HID * HID;
    unsigned short* qb   = wob + (size_t)HID * 2 * HID;
    unsigned short* kb   = qb  + (size_t)T_SEQ * HID;
    unsigned short* vt   = kb  + (size_t)T_SEQ * HID;
    unsigned short* ocat = vt  + (size_t)T_SEQ * HID;

    // L1: conversions + fproj fused (grid-stride, 512 wide)
    prep1<<<dim3(512, 6), 256, 0, stream>>>(
        hs, Wq, Wk, Wv, Wo, Wf, bf, hsb, wqb, wkb, wvb, wob, f);

    // L2: qkv projections (128x64 tile, BK=64, dbuf) -> attention-native layouts
    gemm_mfma_bt<128, 64, 64, 0><<<dim3(HID / 64, T_SEQ / 128, 3), 256, 0, stream>>>(
        hsb, wqb, wkb, wvb, nullptr, qb, kb, vt, T_SEQ, HID, HID);

    // L3: cumsum + knorms fused
    prep2<<<48, 256, 0, stream>>>(f, gcf, gcb, kb, knmax);

    // L4: attention, both dirs (staged, R8 form)
    attn_flash<<<dim3(NT, NH, 2), 256, 0, stream>>>(qb, kb, vt, gcf, gcb, knmax, ocat);

    // L5: out = ocat @ Wo^T (64x64 tile, BK=128, dbuf)
    gemm_mfma_bt<64, 64, 128, 1><<<dim3(HID / 64, T_SEQ / 64, 1), 256, 0, stream>>>(
        ocat, wob, nullptr, nullptr, out, nullptr, nullptr, nullptr,
        T_SEQ, HID, 2 * HID);
}

// Round 14
// 88.891 us; speedup vs baseline: 1.1271x; 1.1208x over previous
//
#include <hip/hip_runtime.h>
#include <math.h>

#define T_SEQ 2048
#define HID   1024
#define NH    16
#define HD    64
#define NT    (T_SEQ / 64)

typedef __attribute__((ext_vector_type(8))) __bf16 bf16x8;
typedef __attribute__((ext_vector_type(4))) float  f32x4;
typedef __attribute__((ext_vector_type(8))) unsigned short u16x8;

#define GPTR(p) (const __attribute__((address_space(1))) void*)(p)
#define SPTR(p) (__attribute__((address_space(3))) void*)(p)

__device__ __forceinline__ unsigned short f2bf(float x) {
    unsigned u = __float_as_uint(x);
    u = (u + 0x7FFF + ((u >> 16) & 1)) >> 16;   // RNE
    return (unsigned short)u;
}
__device__ __forceinline__ float bf2f(unsigned short u) {
    return __uint_as_float((unsigned)u << 16);
}

// ---------------- prep1: f32->bf16 conversions (y<5) + fproj (y==5) ----------------
__global__ __launch_bounds__(256) void prep1(
    const float* __restrict__ hs,
    const float* __restrict__ Wq, const float* __restrict__ Wk,
    const float* __restrict__ Wv, const float* __restrict__ Wo,
    const float* __restrict__ Wf, const float* __restrict__ bfv,
    unsigned short* __restrict__ hsb, unsigned short* __restrict__ wqb,
    unsigned short* __restrict__ wkb, unsigned short* __restrict__ wvb,
    unsigned short* __restrict__ wob, float* __restrict__ f)
{
    const int y = blockIdx.y;
    if (y < 5) {
        const float* in; unsigned short* out; int n;
        switch (y) {
            case 0: in = hs; out = hsb; n = T_SEQ * HID; break;
            case 1: in = Wq; out = wqb; n = HID * HID;   break;
            case 2: in = Wk; out = wkb; n = HID * HID;   break;
            case 3: in = Wv; out = wvb; n = HID * HID;   break;
            default: in = Wo; out = wob; n = HID * 2 * HID; break;
        }
        const int stride = gridDim.x * blockDim.x;
        for (int i = blockIdx.x * blockDim.x + threadIdx.x; i < n / 4; i += stride) {
            float4 v = reinterpret_cast<const float4*>(in)[i];
            ushort4 r;
            r.x = f2bf(v.x); r.y = f2bf(v.y); r.z = f2bf(v.z); r.w = f2bf(v.w);
            reinterpret_cast<ushort4*>(out)[i] = r;
        }
    } else {
        const int t  = blockIdx.x;
        const int h  = threadIdx.x >> 4;
        const int sl = threadIdx.x & 15;
        const float4* hrow = reinterpret_cast<const float4*>(hs + (size_t)t * HID);
        const float4* wrow = reinterpret_cast<const float4*>(Wf + (size_t)h * HID);
        float s = 0.f;
        #pragma unroll
        for (int i = 0; i < 16; ++i) {
            float4 a = hrow[sl + i * 16];
            float4 b = wrow[sl + i * 16];
            s += a.x * b.x + a.y * b.y + a.z * b.z + a.w * b.w;
        }
        s += __shfl_xor(s, 1);
        s += __shfl_xor(s, 2);
        s += __shfl_xor(s, 4);
        s += __shfl_xor(s, 8);
        if (sl == 0) {
            float x = s + bfv[h];
            f[t * NH + h] = (x >= 0.f) ? -log1pf(expf(-x)) : (x - log1pf(expf(x)));
        }
    }
}

// -------- stage one operand tile (rows x BK cols bf16) into LDS (async) --------
template<int NCH, int ROWB>
__device__ __forceinline__ void stage_tile(const unsigned short* __restrict__ G, int K,
                                           int k0, unsigned short* lds, int tid, int w)
{
    #pragma unroll
    for (int j = 0; j < NCH; ++j) {
        const int idxb = j * 4096 + tid * 16;
        const int row  = idxb / ROWB;
        const int kbyt = idxb % ROWB;
        const int col  = (kbyt ^ ((row & 7) << 4)) >> 1;
        const int ldsh = (j * 4096 + w * 1024) >> 1;
        __builtin_amdgcn_global_load_lds(
            GPTR(G + (size_t)row * K + k0 + col), SPTR(lds + ldsh), 16, 0, 0);
    }
}

// ---------------- bf16 MFMA GEMM, 2-phase double-buffered, templated BK ----------------
// EMODE 0 (qkv): z=0 -> qb [T][HID]*0.125; z=1 -> kb [NH][T][64]; z=2 -> vt [NH][64][T].
// EMODE 1: f32 C store. Grid pre-swizzled for XCD locality (nwg%8==0 required).
template<int BM, int BN, int BK, int EMODE>
__global__ __launch_bounds__(256) void gemm_mfma_bt(
    const unsigned short* __restrict__ A,
    const unsigned short* __restrict__ W0, const unsigned short* __restrict__ W1,
    const unsigned short* __restrict__ W2,
    float* __restrict__ C,
    unsigned short* __restrict__ qb, unsigned short* __restrict__ kb,
    unsigned short* __restrict__ vt,
    int M, int N, int K)
{
    const unsigned short* W = blockIdx.z == 0 ? W0 : (blockIdx.z == 1 ? W1 : W2);

    constexpr int FM   = BM / 32;
    constexpr int FN   = BN / 32;
    constexpr int ROWB = BK * 2;
    constexpr int NCHA = BM * BK * 2 / 4096;
    constexpr int NCHB = BN * BK * 2 / 4096;
    constexpr int NKS  = BK / 32;

    __shared__ unsigned short Als[2][BM * BK];
    __shared__ unsigned short Bls[2][BN * BK];

    // XCD-aware bijective swizzle (nwg % 8 == 0)
    const int gx  = gridDim.x;
    const int nwg = gx * gridDim.y;
    const int lin = blockIdx.y * gx + blockIdx.x;
    const int cpx = nwg >> 3;
    const int sw  = (lin & 7) * cpx + (lin >> 3);
    const int bx  = sw % gx;
    const int by  = sw / gx;

    const int tid = threadIdx.x;
    const int w   = tid >> 6;
    const int l   = tid & 63;
    const int bm  = by * BM;
    const int bn  = bx * BN;
    const int wm  = (w >> 1) * (BM / 2);
    const int wn  = (w & 1) * (BN / 2);

    f32x4 acc[FM][FN];
    #pragma unroll
    for (int m = 0; m < FM; ++m)
        #pragma unroll
        for (int n = 0; n < FN; ++n) acc[m][n] = (f32x4){0.f, 0.f, 0.f, 0.f};

    const int frow = l & 15;
    const int kgrp = (l >> 4) * 16;
    const int swz  = (l & 7) << 4;

    const unsigned short* Ag = A + (size_t)bm * K;
    const unsigned short* Wg = W + (size_t)bn * K;

    const int NIT = K / BK;
    stage_tile<NCHA, ROWB>(Ag, K, 0, Als[0], tid, w);
    stage_tile<NCHB, ROWB>(Wg, K, 0, Bls[0], tid, w);
    __syncthreads();           // vmcnt drained -> buf0 ready

    int cur = 0;
    for (int it = 0; it < NIT; ++it) {
        if (it + 1 < NIT) {    // issue next-tile loads before compute (overlap)
            stage_tile<NCHA, ROWB>(Ag, K, (it + 1) * BK, Als[cur ^ 1], tid, w);
            stage_tile<NCHB, ROWB>(Wg, K, (it + 1) * BK, Bls[cur ^ 1], tid, w);
        }
        const unsigned short* Ap = Als[cur];
        const unsigned short* Bp = Bls[cur];
        #pragma unroll
        for (int ks = 0; ks < NKS; ++ks) {
            bf16x8 af[FM], bfr[FN];
            #pragma unroll
            for (int m = 0; m < FM; ++m) {
                const int off = (wm + m * 16 + frow) * ROWB + ((ks * 64 + kgrp) ^ swz);
                af[m] = *reinterpret_cast<const bf16x8*>((const char*)Ap + off);
            }
            #pragma unroll
            for (int n = 0; n < FN; ++n) {
                const int off = (wn + n * 16 + frow) * ROWB + ((ks * 64 + kgrp) ^ swz);
                bfr[n] = *reinterpret_cast<const bf16x8*>((const char*)Bp + off);
            }
            #pragma unroll
            for (int m = 0; m < FM; ++m)
                #pragma unroll
                for (int n = 0; n < FN; ++n)
                    acc[m][n] = __builtin_amdgcn_mfma_f32_16x16x32_bf16(
                        af[m], bfr[n], acc[m][n], 0, 0, 0);
        }
        __syncthreads();       // drains vmcnt: next buffer ready; cur reads done
        cur ^= 1;
    }

    const int r0 = (l >> 4) * 4;
    const int cc = l & 15;
    if (EMODE == 1) {
        #pragma unroll
        for (int m = 0; m < FM; ++m)
            #pragma unroll
            for (int n = 0; n < FN; ++n) {
                float* cp = C + (size_t)(bm + wm + m * 16 + r0) * N + bn + wn + n * 16 + cc;
                #pragma unroll
                for (int r = 0; r < 4; ++r) cp[(size_t)r * N] = acc[m][n][r];
            }
    } else {
        const int z = blockIdx.z;
        if (z == 0) {
            #pragma unroll
            for (int m = 0; m < FM; ++m) {
                const int t0 = bm + wm + m * 16 + r0;
                #pragma unroll
                for (int n = 0; n < FN; ++n) {
                    const int col = bn + wn + n * 16 + cc;
                    #pragma unroll
                    for (int r = 0; r < 4; ++r)
                        qb[(size_t)(t0 + r) * HID + col] = f2bf(acc[m][n][r] * 0.125f);
                }
            }
        } else if (z == 1) {
            #pragma unroll
            for (int m = 0; m < FM; ++m) {
                const int t0 = bm + wm + m * 16 + r0;
                #pragma unroll
                for (int n = 0; n < FN; ++n) {
                    const int col = bn + wn + n * 16 + cc;
                    const int hh  = col >> 6;
                    const int d   = col & 63;
                    #pragma unroll
                    for (int r = 0; r < 4; ++r)
                        kb[(size_t)hh * T_SEQ * HD + (size_t)(t0 + r) * HD + d] =
                            f2bf(acc[m][n][r]);
                }
            }
        } else {
            #pragma unroll
            for (int m = 0; m < FM; ++m) {
                const int t0 = bm + wm + m * 16 + r0;
                #pragma unroll
                for (int n = 0; n < FN; ++n) {
                    const int col = bn + wn + n * 16 + cc;
                    const int hh  = col >> 6;
                    const int d   = col & 63;
                    ushort4 pk;
                    pk.x = f2bf(acc[m][n][0]); pk.y = f2bf(acc[m][n][1]);
                    pk.z = f2bf(acc[m][n][2]); pk.w = f2bf(acc[m][n][3]);
                    *reinterpret_cast<ushort4*>(
                        vt + (size_t)hh * HD * T_SEQ + (size_t)d * T_SEQ + t0) = pk;
                }
            }
        }
    }
}

// ---------------- prep2: cumsum (blocks 0..31) + knorms (blocks 32..47) ----------------
__global__ __launch_bounds__(256) void prep2(const float* __restrict__ f,
                                             float* __restrict__ gcf,
                                             float* __restrict__ gcb,
                                             const unsigned short* __restrict__ kb,
                                             float* __restrict__ knmax)
{
    const int bid = blockIdx.x;
    if (bid < 32) {
        const int h   = bid >> 1;
        const int rev = bid & 1;
        float* out = rev ? gcb : gcf;
        const int wv   = threadIdx.x >> 6;
        const int lane = threadIdx.x & 63;
        __shared__ float wtot[4];
        float vals[8];
        float run = 0.f;
        #pragma unroll
        for (int c = 0; c < 8; ++c) {
            const int p = wv * 512 + c * 64 + lane;
            const int t = rev ? (T_SEQ - 1 - p) : p;
            float x = f[t * NH + h];
            #pragma unroll
            for (int off = 1; off < 64; off <<= 1) {
                float y = __shfl_up(x, off);
                if (lane >= off) x += y;
            }
            vals[c] = run + x;
            run += __shfl(x, 63);
        }
        if (lane == 0) wtot[wv] = run;
        __syncthreads();
        float prefix = 0.f;
        #pragma unroll
        for (int i = 0; i < 4; ++i) prefix += (i < wv) ? wtot[i] : 0.f;
        #pragma unroll
        for (int c = 0; c < 8; ++c) {
            const int p = wv * 512 + c * 64 + lane;
            const int t = rev ? (T_SEQ - 1 - p) : p;
            out[t * NH + h] = vals[c] + prefix;
        }
    } else {
        const int h    = bid - 32;
        const int tid  = threadIdx.x;
        const int wv   = tid >> 6;
        const int lane = tid & 63;
        __shared__ float wmax[4];
        float mx = 0.f;
        for (int t = tid; t < T_SEQ; t += 256) {
            const u16x8* kr = reinterpret_cast<const u16x8*>(
                kb + (size_t)h * T_SEQ * HD + (size_t)t * HD);
            float s = 0.f;
            #pragma unroll
            for (int i = 0; i < 8; ++i) {
                u16x8 v8 = kr[i];
                #pragma unroll
                for (int j = 0; j < 8; ++j) { float x = bf2f(v8[j]); s += x * x; }
            }
            mx = fmaxf(mx, s);
        }
        #pragma unroll
        for (int off = 32; off > 0; off >>= 1) mx = fmaxf(mx, __shfl_xor(mx, off));
        if (lane == 0) wmax[wv] = mx;
        __syncthreads();
        if (tid == 0) {
            float m = fmaxf(fmaxf(wmax[0], wmax[1]), fmaxf(wmax[2], wmax[3]));
            knmax[h] = sqrtf(m);
        }
    }
}

// ---------------- MFMA flash attention, bf16-native inputs (R8 staged form) ----------------
__global__ __launch_bounds__(256) void attn_flash(
    const unsigned short* __restrict__ qb, const unsigned short* __restrict__ kg,
    const unsigned short* __restrict__ vg,
    const float* __restrict__ gcf, const float* __restrict__ gcb,
    const float* __restrict__ knmax,
    unsigned short* __restrict__ ocat)
{
    const int dir = blockIdx.z;
    const float* gc = dir ? gcb : gcf;
    const int h   = blockIdx.y;
    const int qt  = blockIdx.x;
    const int q0  = qt * 64;
    const int tid = threadIdx.x;
    const int w   = tid >> 6;
    const int l   = tid & 63;
    const int lm  = l & 15;
    const int lg  = l >> 4;
    const int swz = (l & 7) << 4;

    __shared__ unsigned short Kls[64 * 64];
    __shared__ unsigned short Vls[64 * 64];
    __shared__ unsigned short Pls[64 * 64];
    __shared__ float gks[64];
    __shared__ float qbs[64];

    const size_t kgbase = (size_t)h * T_SEQ * HD;
    const size_t vgbase = (size_t)h * HD * T_SEQ;

    const int qrow_a = q0 + 16 * w + lm;
    bf16x8 aq[2];
    aq[0] = *reinterpret_cast<const bf16x8*>(qb + (size_t)qrow_a * HID + h * HD + lg * 8);
    aq[1] = *reinterpret_cast<const bf16x8*>(qb + (size_t)qrow_a * HID + h * HD + 32 + lg * 8);
    float qn2 = 0.f;
    #pragma unroll
    for (int ks = 0; ks < 2; ++ks) {
        u16x8 uv = *reinterpret_cast<const u16x8*>(&aq[ks]);
        #pragma unroll
        for (int j = 0; j < 8; ++j) { float x = bf2f(uv[j]); qn2 += x * x; }
    }
    qn2 += __shfl_xor(qn2, 16);
    qn2 += __shfl_xor(qn2, 32);
    if (lg == 0) qbs[16 * w + lm] = sqrtf(qn2) * knmax[h];

    float gq_r[4];
    #pragma unroll
    for (int reg = 0; reg < 4; ++reg)
        gq_r[reg] = gc[(q0 + 16 * w + lg * 4 + reg) * NH + h];

    float mrun[4], lrun[4];
    #pragma unroll
    for (int reg = 0; reg < 4; ++reg) { mrun[reg] = -1e30f; lrun[reg] = 0.f; }
    f32x4 acc[4];
    #pragma unroll
    for (int db = 0; db < 4; ++db) acc[db] = (f32x4){0.f, 0.f, 0.f, 0.f};

    const int stp = dir ? 1 : -1;
    for (int kt = qt; kt >= 0 && kt < NT; kt += stp) {
        const int k0 = kt * 64;

        #pragma unroll
        for (int j = 0; j < 2; ++j) {
            const int idxb = j * 4096 + tid * 16;
            const int row  = idxb >> 7;
            const int kbyt = idxb & 127;
            const int scol = (kbyt ^ ((row & 7) << 4)) >> 1;
            const int ldsh = (j * 4096 + w * 1024) >> 1;
            __builtin_amdgcn_global_load_lds(
                GPTR(kg + kgbase + (size_t)(k0 + row) * HD + scol),
                SPTR(Kls + ldsh), 16, 0, 0);
            __builtin_amdgcn_global_load_lds(
                GPTR(vg + vgbase + (size_t)row * T_SEQ + k0 + scol),
                SPTR(Vls + ldsh), 16, 0, 0);
        }
        if (w == 0)
            __builtin_amdgcn_global_load_lds(
                GPTR(gc + (size_t)(k0 + l) * NH + h), SPTR(gks), 4, 0, 0);
        __syncthreads();

        f32x4 s[4];
        #pragma unroll
        for (int cb = 0; cb < 4; ++cb) {
            bf16x8 b0 = *reinterpret_cast<const bf16x8*>(
                (char*)Kls + (cb * 16 + lm) * 128 + ((lg * 16) ^ swz));
            bf16x8 b1 = *reinterpret_cast<const bf16x8*>(
                (char*)Kls + (cb * 16 + lm) * 128 + ((64 + lg * 16) ^ swz));
            f32x4 z = (f32x4){0.f, 0.f, 0.f, 0.f};
            z = __builtin_amdgcn_mfma_f32_16x16x32_bf16(aq[0], b0, z, 0, 0, 0);
            s[cb] = __builtin_amdgcn_mfma_f32_16x16x32_bf16(aq[1], b1, z, 0, 0, 0);
        }

        float gk_c[4];
        #pragma unroll
        for (int cb = 0; cb < 4; ++cb) gk_c[cb] = gks[cb * 16 + lm];
        float sv[4][4];
        const bool diag = (kt == qt);
        #pragma unroll
        for (int cb = 0; cb < 4; ++cb)
            #pragma unroll
            for (int reg = 0; reg < 4; ++reg) {
                float x = s[cb][reg] + gq_r[reg] - gk_c[cb];
                if (diag) {
                    const int c_loc = cb * 16 + lm;
                    const int r_loc = 16 * w + lg * 4 + reg;
                    const bool valid = dir ? (c_loc >= r_loc) : (c_loc <= r_loc);
                    x = valid ? x : -1e30f;
                }
                sv[cb][reg] = x;
            }

        float corr[4], mnew[4];
        #pragma unroll
        for (int reg = 0; reg < 4; ++reg) {
            float rm = fmaxf(fmaxf(sv[0][reg], sv[1][reg]), fmaxf(sv[2][reg], sv[3][reg]));
            rm = fmaxf(rm, __shfl_xor(rm, 1));
            rm = fmaxf(rm, __shfl_xor(rm, 2));
            rm = fmaxf(rm, __shfl_xor(rm, 4));
            rm = fmaxf(rm, __shfl_xor(rm, 8));
            mnew[reg] = fmaxf(mrun[reg], rm);
            corr[reg] = __expf(mrun[reg] - mnew[reg]);
            mrun[reg] = mnew[reg];
        }
        float psum[4] = {0.f, 0.f, 0.f, 0.f};
        #pragma unroll
        for (int cb = 0; cb < 4; ++cb)
            #pragma unroll
            for (int reg = 0; reg < 4; ++reg) {
                const float p = __expf(sv[cb][reg] - mnew[reg]);
                psum[reg] += p;
                const int r_loc = 16 * w + lg * 4 + reg;
                *reinterpret_cast<unsigned short*>(
                    (char*)Pls + r_loc * 128 + ((cb * 32 + lm * 2) ^ ((r_loc & 7) << 4))) = f2bf(p);
            }
        #pragma unroll
        for (int reg = 0; reg < 4; ++reg) {
            float ps = psum[reg];
            ps += __shfl_xor(ps, 1);
            ps += __shfl_xor(ps, 2);
            ps += __shfl_xor(ps, 4);
            ps += __shfl_xor(ps, 8);
            lrun[reg] = lrun[reg] * corr[reg] + ps;
        }
        #pragma unroll
        for (int db = 0; db < 4; ++db)
            #pragma unroll
            for (int reg = 0; reg < 4; ++reg) acc[db][reg] *= corr[reg];

        bf16x8 ap[2];
        #pragma unroll
        for (int ks = 0; ks < 2; ++ks)
            ap[ks] = *reinterpret_cast<const bf16x8*>(
                (char*)Pls + (16 * w + lm) * 128 + ((ks * 64 + lg * 16) ^ swz));
        #pragma unroll
        for (int db = 0; db < 4; ++db) {
            bf16x8 bv0 = *reinterpret_cast<const bf16x8*>(
                (char*)Vls + (db * 16 + lm) * 128 + ((lg * 16) ^ swz));
            bf16x8 bv1 = *reinterpret_cast<const bf16x8*>(
                (char*)Vls + (db * 16 + lm) * 128 + ((64 + lg * 16) ^ swz));
            acc[db] = __builtin_amdgcn_mfma_f32_16x16x32_bf16(ap[0], bv0, acc[db], 0, 0, 0);
            acc[db] = __builtin_amdgcn_mfma_f32_16x16x32_bf16(ap[1], bv1, acc[db], 0, 0, 0);
        }

        const int nkt = kt + stp;
        if (nkt >= 0 && nkt < NT) {
            const float gkedge = dir ? gc[(nkt * 64) * NH + h]
                                     : gc[(nkt * 64 + 63) * NH + h];
            int pred = 0;
            #pragma unroll
            for (int reg = 0; reg < 4; ++reg) {
                const float qbv = qbs[16 * w + lg * 4 + reg];
                pred |= (qbv + gq_r[reg] - gkedge) >= (mrun[reg] - 15.f);
            }
            if (!__syncthreads_or(pred)) break;
        }
    }

    float inv[4];
    #pragma unroll
    for (int reg = 0; reg < 4; ++reg) inv[reg] = 1.f / lrun[reg];
    #pragma unroll
    for (int db = 0; db < 4; ++db)
        #pragma unroll
        for (int reg = 0; reg < 4; ++reg) {
            const int row = q0 + 16 * w + lg * 4 + reg;
            const int col = db * 16 + lm;
            ocat[(size_t)row * (2 * HID) + dir * HID + h * HD + col] =
                f2bf(acc[db][reg] * inv[reg]);
        }
}

// ---------------- launch ----------------
extern "C" void kernel_launch(void* const* d_in, const int* in_sizes, int n_in,
                              void* d_out, int out_size, void* d_ws, size_t ws_size,
                              hipStream_t stream)
{
    (void)in_sizes; (void)n_in; (void)out_size; (void)ws_size;
    const float* hs = (const float*)d_in[0];
    const float* Wq = (const float*)d_in[1];
    const float* Wk = (const float*)d_in[2];
    const float* Wv = (const float*)d_in[3];
    const float* Wf = (const float*)d_in[4];
    const float* bf = (const float*)d_in[5];
    const float* Wo = (const float*)d_in[6];
    float* out = (float*)d_out;

    float* ws    = (float*)d_ws;
    float* f     = ws;
    float* gcf   = f   + (size_t)T_SEQ * NH;
    float* gcb   = gcf + (size_t)T_SEQ * NH;
    float* knmax = gcb + (size_t)T_SEQ * NH;
    unsigned short* hsb  = (unsigned short*)(knmax + 64);
    unsigned short* wqb  = hsb + (size_t)T_SEQ * HID;
    unsigned short* wkb  = wqb + (size_t)HID * HID;
    unsigned short* wvb  = wkb + (size_t)HID * HID;
    unsigned short* wob  = wvb + (size_t)HID * HID;
    unsigned short* qb   = wob + (size_t)HID * 2 * HID;
    unsigned short* kb   = qb  + (size_t)T_SEQ * HID;
    unsigned short* vt   = kb  + (size_t)T_SEQ * HID;
    unsigned short* ocat = vt  + (size_t)T_SEQ * HID;

    // L1: conversions + fproj fused
    prep1<<<dim3(2048, 6), 256, 0, stream>>>(
        hs, Wq, Wk, Wv, Wo, Wf, bf, hsb, wqb, wkb, wvb, wob, f);

    // L2: qkv projections (128x64 tile, BK=64, dbuf) -> attention-native layouts
    gemm_mfma_bt<128, 64, 64, 0><<<dim3(HID / 64, T_SEQ / 128, 3), 256, 0, stream>>>(
        hsb, wqb, wkb, wvb, nullptr, qb, kb, vt, T_SEQ, HID, HID);

    // L3: cumsum + knorms fused
    prep2<<<48, 256, 0, stream>>>(f, gcf, gcb, kb, knmax);

    // L4: attention, both dirs (staged, R8 form)
    attn_flash<<<dim3(NT, NH, 2), 256, 0, stream>>>(qb, kb, vt, gcf, gcb, knmax, ocat);

    // L5: out = ocat @ Wo^T (64x64 tile, BK=128, dbuf)
    gemm_mfma_bt<64, 64, 128, 1><<<dim3(HID / 64, T_SEQ / 64, 1), 256, 0, stream>>>(
        ocat, wob, nullptr, nullptr, out, nullptr, nullptr, nullptr,
        T_SEQ, HID, 2 * HID);
}